// Round 10
// baseline (319.098 us; speedup 1.0000x reference)
//
#include <hip/hip_runtime.h>

// AttentionHead: B=8, N=2048, D=1024
// qkv = x @ W^T + b ; q,k,v split ; S = qk^T/32 ; P = softmax(S) ; out = P v
// Pipeline: cvt -> qkv_gemm256 (writes Q, K, V^T) -> scores_gemm256 (bf16 S)
//           -> softmax_bf16 (in-place, wave-per-row) -> pv_gemm256
// GEMMs: round-9 8-phase skeleton (stage slots / vmcnt(6)@P4,P8 / barriers
//   unchanged, race-freedom proof carries over), MFMA switched to
//   v_mfma_f32_32x32x16_bf16 (round-10): 2382 TF ceiling (+15% vs 16x16),
//   8 MFMA/phase instead of 16 (half the issue slots), same LDS bytes.
//   Frags: A/B row=lane&31, kbase=(lane>>5)*8, 4 k-slices of 16 per K-tile.
//   C/D: col=lane&31, row=(reg&3)+8*(reg>>2)+4*(lane>>5)  [m74/m101 verified].
// Workspace layout (peak 198 MiB):
//   [0,32MB)    x_bf          [32,38MB)  W_bf
//   [38,70MB)   Q bf16        [70,102MB) K bf16
//   [102,166MB) S bf16 rows stride 2048 (softmax in-place -> P)
//   [166,198MB) Vt bf16 [b][d][n]

#define AS1 __attribute__((address_space(1)))
#define AS3 __attribute__((address_space(3)))

typedef __bf16 bfrag  __attribute__((ext_vector_type(8)));
typedef float  f32x16 __attribute__((ext_vector_type(16)));
typedef __bf16 bf16x4 __attribute__((ext_vector_type(4)));
typedef __bf16 bf16x8 __attribute__((ext_vector_type(8)));

// ---------------- f32 -> bf16 convert, x4 vectorized ----------------
__global__ __launch_bounds__(256) void cvt_f32_bf16(const float* __restrict__ in,
                                                    __bf16* __restrict__ out, int n4) {
  int i = blockIdx.x * blockDim.x + threadIdx.x;
  int stride = gridDim.x * blockDim.x;
  for (; i < n4; i += stride) {
    float4 v = ((const float4*)in)[i];
    bf16x4 o;
    o[0] = (__bf16)v.x; o[1] = (__bf16)v.y; o[2] = (__bf16)v.z; o[3] = (__bf16)v.w;
    ((bf16x4*)out)[i] = o;
  }
}

// =================== 256x256 8-phase GEMM mainloop (32x32x16 MFMA) ===========
// C[m][o] = sum_k A[m][k] * B[o][k]  (both K-major, B^T form)
// 512 threads = 8 waves (wr = wid>>2 in {0,1}, wc = wid&3 in {0..3}).
// LDS 128 KiB: buf{0,1} x (A[256][64] | B[256][64]) bf16, tile t -> buf t&1.
// Half-regions (8192 elems): h0=A rows 0-127, h1=A rows 128-255, h2=B rows
// 0-127, h3=B rows 128-255 at elem offset h*8192.
// Per-wave output 128x64 = 4 Mfrags x 2 Nfrags of 32. Quadrant (qa,qb) =
// 64x32 = 2 Mfrags x 1 Nfrag x 4 ks = 8 MFMA32. Zigzag (00,01,11,10); regs
// held across phases -> 24 ds_read_b128 per wave per K-tile (minimum).
// Swizzle: LDS[r][c] = G[r][c ^ ((r&7)<<3)], inverse-applied on global source.

__device__ __forceinline__ void stage_half(
    const __bf16* __restrict__ Atile, const __bf16* __restrict__ Btile,
    int lda, int ldb, __bf16* lds, int tid, int te, int h) {
  const int kt = te * 64;
  const __bf16* src = (h < 2) ? Atile : Btile;
  const int ld = (h < 2) ? lda : ldb;
  const int row0 = (h & 1) * 128;
  __bf16* dst = lds + (te & 1) * 32768 + h * 8192;
#pragma unroll
  for (int l = 0; l < 2; ++l) {
    const int y = l * 4096 + tid * 8;                  // linear LDS dest (uniform base + lane*16B)
    const int r = y >> 6;                              // row within half (0..127)
    const int c = ((tid & 7) * 8) ^ ((r & 7) << 3);    // inverse-swizzled source col
    __builtin_amdgcn_global_load_lds((AS1 void*)(src + (size_t)(row0 + r) * ld + kt + c),
                                     (AS3 void*)(dst + y), 16, 0, 0);
  }
}

// a[mf][ks]: A rows QA*128 + wr*64 + mf*32 + (lane&31), k-slice ks (K=16 each)
template <int QA>
__device__ __forceinline__ void rd_a32(const __bf16* lds, int bufoff, int aRowBase,
                                       const int ck[4], bfrag a[2][4]) {
#pragma unroll
  for (int mf = 0; mf < 2; ++mf)
#pragma unroll
    for (int ks = 0; ks < 4; ++ks)
      a[mf][ks] = *(const bfrag*)&lds[bufoff + QA * 8192 + aRowBase + mf * 2048 + ck[ks]];
}

// b[ks]: B rows QB*128 + wc*32 + (lane&31)
template <int QB>
__device__ __forceinline__ void rd_b32(const __bf16* lds, int bufoff, int bRowBase,
                                       const int ck[4], bfrag b[4]) {
#pragma unroll
  for (int ks = 0; ks < 4; ++ks)
    b[ks] = *(const bfrag*)&lds[bufoff + QB * 8192 + bRowBase + ck[ks]];
}

// One phase tail: [vmcnt(6)] barrier; lgkmcnt(0); setprio(1) 8 MFMA32 setprio(0); barrier.
#define PH(QA, QB, BREG, DOVM)                                                 \
  {                                                                            \
    if (DOVM) asm volatile("s_waitcnt vmcnt(6)" ::: "memory");                 \
    __builtin_amdgcn_s_barrier();                                              \
    asm volatile("s_waitcnt lgkmcnt(0)" ::: "memory");                         \
    __builtin_amdgcn_s_setprio(1);                                             \
    _Pragma("unroll") for (int mf_ = 0; mf_ < 2; ++mf_)                        \
    _Pragma("unroll") for (int ks_ = 0; ks_ < 4; ++ks_)                        \
      acc[(QA) * 2 + mf_][(QB)] = __builtin_amdgcn_mfma_f32_32x32x16_bf16(     \
          a[mf_][ks_], BREG[ks_], acc[(QA) * 2 + mf_][(QB)], 0, 0, 0);         \
    __builtin_amdgcn_s_setprio(0);                                             \
    __builtin_amdgcn_s_barrier();                                              \
    __builtin_amdgcn_sched_barrier(0);                                         \
  }

#define STG(TE, H) stage_half(Atile, Btile, lda, ldb, lds, tid, (TE), (H))

__device__ __forceinline__ void gemm256_mainloop(
    const __bf16* __restrict__ Atile, const __bf16* __restrict__ Btile,
    int lda, int ldb, int K, __bf16* lds, f32x16 acc[4][2]) {
  const int tid  = threadIdx.x;
  const int lane = tid & 63;
  const int wid  = tid >> 6;
  const int wr   = wid >> 2, wc = wid & 3;
  const int fr   = lane & 31;           // frag row/col (32-wide)
  const int fk   = (lane >> 5) * 8;     // k-base 0/8 within a 16-k slice
  const int swz  = (fr & 7) << 3;
  int ck[4];
#pragma unroll
  for (int ks = 0; ks < 4; ++ks) ck[ks] = (ks * 16 + fk) ^ swz;  // swizzled frag cols
  const int aRowBase = (wr * 64 + fr) * 64;
  const int bRowBase = 16384 + (wc * 32 + fr) * 64;
  const int nT = K >> 6;

  // prologue (round-9 proven): A0,B0,B1,A1 of T0; A0,B0,B1 of T1.
  // vmcnt(6) -> all of T0 confirmed; 3 halves (T1's) in flight.
  STG(0, 0); STG(0, 2); STG(0, 3); STG(0, 1);
  STG(1, 0); STG(1, 2); STG(1, 3);
  asm volatile("s_waitcnt vmcnt(6)" ::: "memory");
  __builtin_amdgcn_s_barrier();

  const int nIter = nT >> 1;
#pragma unroll 1
  for (int i = 0; i < nIter; ++i) {
    const int t1  = 2 * i + 1;
    const int t2e = (2 * i + 2 < nT) ? (2 * i + 2) : (2 * i);      // tail wrap,
    const int t3e = (2 * i + 3 < nT) ? (2 * i + 3) : (2 * i + 1);  // same parity
    bfrag a[2][4], b0f[4], b1f[4];
    // P1 (qa0,qb0): read a0 (8) + b0 (4); stage A1(t1)
    rd_a32<0>(lds, 0, aRowBase, ck, a);
    rd_b32<0>(lds, 0, bRowBase, ck, b0f);
    STG(t1, 1);
    PH(0, 0, b0f, false)
    // P2 (qa0,qb1): read b1 (4); a held; stage A0(t2)
    rd_b32<1>(lds, 0, bRowBase, ck, b1f);
    STG(t2e, 0);
    PH(0, 1, b1f, false)
    // P3 (qa1,qb1): read a1 (8); b1 held; stage B0(t2)
    rd_a32<1>(lds, 0, aRowBase, ck, a);
    STG(t2e, 2);
    PH(1, 1, b1f, false)
    // P4 (qa1,qb0): no reads (a1,b0 held); stage B1(t2); vmcnt(6)
    STG(t2e, 3);
    PH(1, 0, b0f, true)
    // P5 (qa0,qb0) on buf1: read a0+b0; stage A1(t2)
    rd_a32<0>(lds, 32768, aRowBase, ck, a);
    rd_b32<0>(lds, 32768, bRowBase, ck, b0f);
    STG(t2e, 1);
    PH(0, 0, b0f, false)
    // P6 (qa0,qb1): read b1; stage A0(t3)
    rd_b32<1>(lds, 32768, bRowBase, ck, b1f);
    STG(t3e, 0);
    PH(0, 1, b1f, false)
    // P7 (qa1,qb1): read a1; stage B0(t3)
    rd_a32<1>(lds, 32768, aRowBase, ck, a);
    STG(t3e, 2);
    PH(1, 1, b1f, false)
    // P8 (qa1,qb0): no reads; stage B1(t3); vmcnt(6)
    STG(t3e, 3);
    PH(1, 0, b0f, true)
  }
}

#define ACC_ZERO()                                                             \
  f32x16 acc[4][2];                                                            \
  _Pragma("unroll") for (int m = 0; m < 4; ++m)                                \
  _Pragma("unroll") for (int n = 0; n < 2; ++n) acc[m][n] = (f32x16)(0.0f);

// Epilogue mapping for acc[i][j] (i: qa=i>>1, mf=i&1; j=qb), reg in [0,16):
// row = brow + qa*128 + wr*64 + mf*32 + (reg&3) + 8*(reg>>2) + 4*(lane>>5)
// col = bcol + qb*128 + wc*32 + (lane&31)

// ---------------- kernel 1: qkv projection (V written transposed) ----------
__global__ __launch_bounds__(512, 2) void qkv_gemm256(
    const __bf16* __restrict__ Abf, const __bf16* __restrict__ Wbf,
    const float* __restrict__ bias,
    __bf16* __restrict__ Q, __bf16* __restrict__ Ko, __bf16* __restrict__ Vt) {
  __shared__ __bf16 lds[65536];
  ACC_ZERO();
  int bid = (int)blockIdx.x;
  bid = (bid & 7) * 96 + (bid >> 3);          // XCD swizzle (768 % 8 == 0, bijective)
  const int brow = (bid / 12) * 256;
  const int bcol = (bid % 12) * 256;
  gemm256_mainloop(Abf + (size_t)brow * 1024, Wbf + (size_t)bcol * 1024,
                   1024, 1024, 1024, lds, acc);
  const int lane = threadIdx.x & 63, wid = threadIdx.x >> 6;
  const int wr = wid >> 2, wc = wid & 3;
  const int fr = lane & 31, hi4 = (lane >> 5) * 4;
  const int region = bcol >> 10;              // 0=Q,1=K,2=V (tile within one region)
  if (region < 2) {
    __bf16* dst = region == 0 ? Q : Ko;
    const float scale = region == 0 ? 0.03125f : 1.0f;  // fold 1/sqrt(1024) into Q
#pragma unroll
    for (int j = 0; j < 2; ++j) {
      const int col = bcol + j * 128 + wc * 32 + fr;
      const int o = col & 1023;
      const float bv = bias[col];
#pragma unroll
      for (int i = 0; i < 4; ++i) {
        const int rbase = brow + (i >> 1) * 128 + wr * 64 + (i & 1) * 32 + hi4;
#pragma unroll
        for (int reg = 0; reg < 16; ++reg) {
          const int mg = rbase + (reg & 3) + 8 * (reg >> 2);
          dst[(size_t)mg * 1024 + o] = (__bf16)((acc[i][j][reg] + bv) * scale);
        }
      }
    }
  } else {
    // V: write transposed Vt[b][d][n]; 4 consecutive rows (reg&3) pack into 8B
#pragma unroll
    for (int j = 0; j < 2; ++j) {
      const int col = bcol + j * 128 + wc * 32 + fr;
      const int o = col & 1023;                // d index
      const float bv = bias[col];
#pragma unroll
      for (int i = 0; i < 4; ++i) {
        const int rbase = brow + (i >> 1) * 128 + wr * 64 + (i & 1) * 32 + hi4;
#pragma unroll
        for (int g = 0; g < 4; ++g) {
          const int mg0 = rbase + 8 * g;
          const int b = mg0 >> 11, nr = mg0 & 2047;
          bf16x4 v;
#pragma unroll
          for (int s = 0; s < 4; ++s) v[s] = (__bf16)(acc[i][j][g * 4 + s] + bv);
          *(bf16x4*)&Vt[(size_t)b * 2097152 + (size_t)o * 2048 + nr] = v;
        }
      }
    }
  }
}

// ---------------- kernel 2: scores S = Q K^T (Q pre-scaled), bf16 out ------
__global__ __launch_bounds__(512, 2) void scores_gemm256(const __bf16* __restrict__ Q,
                                                         const __bf16* __restrict__ Kb,
                                                         __bf16* __restrict__ S) {
  __shared__ __bf16 lds[65536];
  ACC_ZERO();
  int bid = (int)blockIdx.x;                  // 512 blocks: XCD swizzle, batch-per-XCD
  const int wg = (bid & 7) * 64 + (bid >> 3);
  const int brow = (wg & 7) * 256, bcol = ((wg >> 3) & 7) * 256, z = wg >> 6;
  gemm256_mainloop(Q + (size_t)z * 2048 * 1024 + (size_t)brow * 1024,
                   Kb + (size_t)z * 2048 * 1024 + (size_t)bcol * 1024,
                   1024, 1024, 1024, lds, acc);
  const int lane = threadIdx.x & 63, wid = threadIdx.x >> 6;
  const int wr = wid >> 2, wc = wid & 3;
  const int fr = lane & 31, hi4 = (lane >> 5) * 4;
#pragma unroll
  for (int j = 0; j < 2; ++j) {
    const int o = bcol + j * 128 + wc * 32 + fr;
#pragma unroll
    for (int i = 0; i < 4; ++i) {
      const int rbase = brow + (i >> 1) * 128 + wr * 64 + (i & 1) * 32 + hi4;
#pragma unroll
      for (int reg = 0; reg < 16; ++reg) {
        const int mg = rbase + (reg & 3) + 8 * (reg >> 2);
        S[((size_t)(z * 2048 + mg)) * 2048 + o] = (__bf16)acc[i][j][reg];
      }
    }
  }
}

// ---------------- kernel 3: in-place bf16 row softmax (wave per row) -------
__global__ __launch_bounds__(256) void softmax_bf16(__bf16* S) {
  const int row = blockIdx.x * 4 + (threadIdx.x >> 6);
  const int lane = threadIdx.x & 63;
  __bf16* s = S + (size_t)row * 2048 + lane * 8;
  float f[32];
#pragma unroll
  for (int c = 0; c < 4; ++c) {
    bf16x8 v = *(const bf16x8*)&s[c * 512];
#pragma unroll
    for (int j = 0; j < 8; ++j) f[c * 8 + j] = (float)v[j];
  }
  float m = f[0];
#pragma unroll
  for (int j = 1; j < 32; ++j) m = fmaxf(m, f[j]);
#pragma unroll
  for (int off = 32; off; off >>= 1) m = fmaxf(m, __shfl_xor(m, off, 64));
  float sum = 0.f;
#pragma unroll
  for (int j = 0; j < 32; ++j) { f[j] = __expf(f[j] - m); sum += f[j]; }
#pragma unroll
  for (int off = 32; off; off >>= 1) sum += __shfl_xor(sum, off, 64);
  const float inv = 1.0f / sum;
#pragma unroll
  for (int c = 0; c < 4; ++c) {
    bf16x8 o;
#pragma unroll
    for (int j = 0; j < 8; ++j) o[j] = (__bf16)(f[c * 8 + j] * inv);
    *(bf16x8*)&s[c * 512] = o;
  }
}

// ---------------- kernel 4: out = P @ V  (via Vt, B^T form) ----------------
__global__ __launch_bounds__(512, 2) void pv_gemm256(const __bf16* __restrict__ P,
                                                     const __bf16* __restrict__ Vt,
                                                     float* __restrict__ O) {
  __shared__ __bf16 lds[65536];
  ACC_ZERO();
  int bid = (int)blockIdx.x;                  // 256 blocks: XCD swizzle, batch-per-XCD
  const int wg = (bid & 7) * 32 + (bid >> 3);
  const int brow = (wg & 7) * 256, bcol = ((wg >> 3) & 3) * 256, z = wg >> 5;
  gemm256_mainloop(P + (size_t)(z * 2048 + brow) * 2048,
                   Vt + (size_t)z * 1024 * 2048 + (size_t)bcol * 2048,
                   2048, 2048, 2048, lds, acc);
  const int lane = threadIdx.x & 63, wid = threadIdx.x >> 6;
  const int wr = wid >> 2, wc = wid & 3;
  const int fr = lane & 31, hi4 = (lane >> 5) * 4;
#pragma unroll
  for (int j = 0; j < 2; ++j) {
    const int o = bcol + j * 128 + wc * 32 + fr;
#pragma unroll
    for (int i = 0; i < 4; ++i) {
      const int rbase = brow + (i >> 1) * 128 + wr * 64 + (i & 1) * 32 + hi4;
#pragma unroll
      for (int reg = 0; reg < 16; ++reg) {
        const int mg = rbase + (reg & 3) + 8 * (reg >> 2);
        O[((size_t)(z * 2048 + mg)) * 1024 + o] = acc[i][j][reg];
      }
    }
  }
}

extern "C" void kernel_launch(void* const* d_in, const int* in_sizes, int n_in,
                              void* d_out, int out_size, void* d_ws, size_t ws_size,
                              hipStream_t stream) {
  (void)in_sizes; (void)n_in; (void)out_size; (void)ws_size;
  const float* x    = (const float*)d_in[0];
  const float* W    = (const float*)d_in[1];
  const float* bias = (const float*)d_in[2];
  float* out = (float*)d_out;
  char* ws = (char*)d_ws;
  const size_t MB = 1u << 20;
  __bf16* x_bf = (__bf16*)(ws + 0);
  __bf16* W_bf = (__bf16*)(ws + 32 * MB);
  __bf16* Qb   = (__bf16*)(ws + 38 * MB);
  __bf16* Kb   = (__bf16*)(ws + 70 * MB);
  __bf16* S    = (__bf16*)(ws + 102 * MB);   // bf16 scores, softmax in-place -> P
  __bf16* Vt   = (__bf16*)(ws + 166 * MB);   // V^T, written by qkv epilogue

  cvt_f32_bf16<<<2048, 256, 0, stream>>>(x, x_bf, 16777216 / 4);
  cvt_f32_bf16<<<1024, 256, 0, stream>>>(W, W_bf, 3145728 / 4);
  qkv_gemm256<<<768, 512, 0, stream>>>(x_bf, W_bf, bias, Qb, Kb, Vt);
  scores_gemm256<<<512, 512, 0, stream>>>(Qb, Kb, S);
  softmax_bf16<<<4096, 256, 0, stream>>>(S);
  pv_gemm256<<<256, 512, 0, stream>>>(S, Vt, out);
}

// Round 11
// 256.508 us; speedup vs baseline: 1.2440x; 1.2440x over previous
//
#include <hip/hip_runtime.h>

// AttentionHead: B=8, N=2048, D=1024
// qkv = x @ W^T + b ; q,k,v split ; S = qk^T/32 ; P = softmax(S) ; out = P v
// Round-11 pipeline (softmax pass ELIMINATED via fixed-offset exp + deferred
// normalization: softmax(S) = exp(S-16)/sum(exp(S-16)); |S|<~6 so exp(S-16)
// is bf16-safe; scores epilogue writes Pu=exp(S-16) and atomically accumulates
// row sums; pv epilogue multiplies by 1/rowsum):
//   cvt_fused (x->bf16, W->bf16, rowsum=0) -> qkv_gemm256 (writes Q, K, V^T)
//   -> scores_gemm256 (writes Pu bf16 + rowsum atomics) -> pv_gemm256 (x 1/rs)
// GEMMs: round-9 verified 8-phase 256x256 schedule (16x16x32 MFMA; round-10's
//   32x32 variant reverted: it caused 9.4M LDS bank conflicts).
// Workspace layout (peak 198 MiB + 64 KiB):
//   [0,32MB)    x_bf          [32,38MB)  W_bf
//   [38,70MB)   Q bf16        [70,102MB) K bf16
//   [102,166MB) Pu bf16 rows stride 2048
//   [166,198MB) Vt bf16 [b][d][n]
//   [198MB,+64KB) rowsum f32[16384]

#define AS1 __attribute__((address_space(1)))
#define AS3 __attribute__((address_space(3)))

typedef __bf16 bfrag  __attribute__((ext_vector_type(8)));
typedef float  ffrag  __attribute__((ext_vector_type(4)));
typedef __bf16 bf16x4 __attribute__((ext_vector_type(4)));

// ------- fused convert: x->bf16, W->bf16, zero rowsum (must precede scores) --
__global__ __launch_bounds__(256) void cvt_fused(const float* __restrict__ x,
                                                 const float* __restrict__ W,
                                                 __bf16* __restrict__ xb,
                                                 __bf16* __restrict__ Wb,
                                                 float* __restrict__ rowsum) {
  const int gid = blockIdx.x * 256 + threadIdx.x;
  const int stride = gridDim.x * 256;
  for (int k = gid; k < 4194304; k += stride) {
    float4 v = ((const float4*)x)[k];
    bf16x4 o;
    o[0] = (__bf16)v.x; o[1] = (__bf16)v.y; o[2] = (__bf16)v.z; o[3] = (__bf16)v.w;
    ((bf16x4*)xb)[k] = o;
  }
  for (int k = gid; k < 786432; k += stride) {
    float4 v = ((const float4*)W)[k];
    bf16x4 o;
    o[0] = (__bf16)v.x; o[1] = (__bf16)v.y; o[2] = (__bf16)v.z; o[3] = (__bf16)v.w;
    ((bf16x4*)Wb)[k] = o;
  }
  for (int k = gid; k < 16384; k += stride) rowsum[k] = 0.0f;
}

// =================== 256x256 8-phase GEMM mainloop (round-9, verified) =======
__device__ __forceinline__ void stage_half(
    const __bf16* __restrict__ Atile, const __bf16* __restrict__ Btile,
    int lda, int ldb, __bf16* lds, int tid, int te, int h) {
  const int kt = te * 64;
  const __bf16* src = (h < 2) ? Atile : Btile;
  const int ld = (h < 2) ? lda : ldb;
  const int row0 = (h & 1) * 128;
  __bf16* dst = lds + (te & 1) * 32768 + h * 8192;
#pragma unroll
  for (int l = 0; l < 2; ++l) {
    const int y = l * 4096 + tid * 8;                  // linear LDS dest (uniform base + lane*16B)
    const int r = y >> 6;                              // row within half (0..127)
    const int c = ((tid & 7) * 8) ^ ((r & 7) << 3);    // inverse-swizzled source col
    __builtin_amdgcn_global_load_lds((AS1 void*)(src + (size_t)(row0 + r) * ld + kt + c),
                                     (AS3 void*)(dst + y), 16, 0, 0);
  }
}

template <int QA>
__device__ __forceinline__ void rd_a(const __bf16* lds, int bufoff, int aRowBase,
                                     int ck0, int ck1, bfrag a[4][2]) {
#pragma unroll
  for (int m = 0; m < 4; ++m) {
    const int off = bufoff + aRowBase + QA * 8192 + m * 1024;
    a[m][0] = *(const bfrag*)&lds[off + ck0];
    a[m][1] = *(const bfrag*)&lds[off + ck1];
  }
}

template <int QB>
__device__ __forceinline__ void rd_bq(const __bf16* lds, int bufoff, int bRowBase,
                                      int ck0, int ck1, bfrag b[2][2]) {
#pragma unroll
  for (int n = 0; n < 2; ++n) {
    const int off = bufoff + bRowBase + QB * 8192 + n * 1024;
    b[n][0] = *(const bfrag*)&lds[off + ck0];
    b[n][1] = *(const bfrag*)&lds[off + ck1];
  }
}

#define PH(QA, QB, BREG, DOVM)                                                 \
  {                                                                            \
    if (DOVM) asm volatile("s_waitcnt vmcnt(6)" ::: "memory");                 \
    __builtin_amdgcn_s_barrier();                                              \
    asm volatile("s_waitcnt lgkmcnt(0)" ::: "memory");                         \
    __builtin_amdgcn_s_setprio(1);                                             \
    _Pragma("unroll") for (int m_ = 0; m_ < 4; ++m_)                           \
    _Pragma("unroll") for (int n_ = 0; n_ < 2; ++n_)                           \
    _Pragma("unroll") for (int ks_ = 0; ks_ < 2; ++ks_)                        \
      acc[(QA) * 4 + m_][(QB) * 2 + n_] =                                      \
          __builtin_amdgcn_mfma_f32_16x16x32_bf16(                             \
              a[m_][ks_], BREG[n_][ks_], acc[(QA) * 4 + m_][(QB) * 2 + n_],    \
              0, 0, 0);                                                        \
    __builtin_amdgcn_s_setprio(0);                                             \
    __builtin_amdgcn_s_barrier();                                              \
    __builtin_amdgcn_sched_barrier(0);                                         \
  }

#define STG(TE, H) stage_half(Atile, Btile, lda, ldb, lds, tid, (TE), (H))

__device__ __forceinline__ void gemm256_mainloop(
    const __bf16* __restrict__ Atile, const __bf16* __restrict__ Btile,
    int lda, int ldb, int K, __bf16* lds, ffrag acc[8][4]) {
  const int tid  = threadIdx.x;
  const int lane = tid & 63;
  const int wid  = tid >> 6;
  const int wr   = wid >> 2, wc = wid & 3;
  const int fr   = lane & 15;
  const int fk   = (lane >> 4) * 8;
  const int swz  = (fr & 7) << 3;
  const int ck0  = fk ^ swz;            // ks=0 frag col (swizzled)
  const int ck1  = (32 + fk) ^ swz;     // ks=1
  const int aRowBase = (wr * 64 + fr) * 64;
  const int bRowBase = 16384 + (wc * 32 + fr) * 64;
  const int nT = K >> 6;

  // prologue: A0,B0,B1,A1 of T0; A0,B0,B1 of T1. vmcnt(6) -> T0 confirmed.
  STG(0, 0); STG(0, 2); STG(0, 3); STG(0, 1);
  STG(1, 0); STG(1, 2); STG(1, 3);
  asm volatile("s_waitcnt vmcnt(6)" ::: "memory");
  __builtin_amdgcn_s_barrier();

  const int nIter = nT >> 1;
#pragma unroll 1
  for (int i = 0; i < nIter; ++i) {
    const int t1  = 2 * i + 1;
    const int t2e = (2 * i + 2 < nT) ? (2 * i + 2) : (2 * i);      // tail wrap,
    const int t3e = (2 * i + 3 < nT) ? (2 * i + 3) : (2 * i + 1);  // same parity
    bfrag a[4][2], b0f[2][2], b1f[2][2];
    rd_a<0>(lds, 0, aRowBase, ck0, ck1, a);
    rd_bq<0>(lds, 0, bRowBase, ck0, ck1, b0f);
    STG(t1, 1);
    PH(0, 0, b0f, false)
    rd_bq<1>(lds, 0, bRowBase, ck0, ck1, b1f);
    STG(t2e, 0);
    PH(0, 1, b1f, false)
    rd_a<1>(lds, 0, aRowBase, ck0, ck1, a);
    STG(t2e, 2);
    PH(1, 1, b1f, false)
    STG(t2e, 3);
    PH(1, 0, b0f, true)
    rd_a<0>(lds, 32768, aRowBase, ck0, ck1, a);
    rd_bq<0>(lds, 32768, bRowBase, ck0, ck1, b0f);
    STG(t2e, 1);
    PH(0, 0, b0f, false)
    rd_bq<1>(lds, 32768, bRowBase, ck0, ck1, b1f);
    STG(t3e, 0);
    PH(0, 1, b1f, false)
    rd_a<1>(lds, 32768, aRowBase, ck0, ck1, a);
    STG(t3e, 2);
    PH(1, 1, b1f, false)
    STG(t3e, 3);
    PH(1, 0, b0f, true)
  }
}

#define ACC_ZERO()                                                             \
  ffrag acc[8][4];                                                             \
  _Pragma("unroll") for (int m = 0; m < 8; ++m)                                \
  _Pragma("unroll") for (int n = 0; n < 4; ++n) acc[m][n] = (ffrag)(0.0f);

// Epilogue mapping for acc[i][j]: qa=i>>2, m=i&3, qb=j>>1, n=j&1.
// row = brow + qa*128 + wr*64 + m*16 + (lane>>4)*4 + r
// col = bcol + qb*128 + wc*32 + n*16 + (lane&15)

// ---------------- kernel 1: qkv projection (V written transposed) ----------
__global__ __launch_bounds__(512, 2) void qkv_gemm256(
    const __bf16* __restrict__ Abf, const __bf16* __restrict__ Wbf,
    const float* __restrict__ bias,
    __bf16* __restrict__ Q, __bf16* __restrict__ Ko, __bf16* __restrict__ Vt) {
  __shared__ __bf16 lds[65536];
  ACC_ZERO();
  int bid = (int)blockIdx.x;
  bid = (bid & 7) * 96 + (bid >> 3);          // XCD swizzle (768 % 8 == 0, bijective)
  const int brow = (bid / 12) * 256;
  const int bcol = (bid % 12) * 256;
  gemm256_mainloop(Abf + (size_t)brow * 1024, Wbf + (size_t)bcol * 1024,
                   1024, 1024, 1024, lds, acc);
  const int lane = threadIdx.x & 63, wid = threadIdx.x >> 6;
  const int wr = wid >> 2, wc = wid & 3;
  const int region = bcol >> 10;              // 0=Q,1=K,2=V (tile within one region)
  if (region < 2) {
    __bf16* dst = region == 0 ? Q : Ko;
    const float scale = region == 0 ? 0.03125f : 1.0f;  // fold 1/sqrt(1024) into Q
#pragma unroll
    for (int j = 0; j < 4; ++j) {
      const int qb = j >> 1, n = j & 1;
      const int col = bcol + qb * 128 + wc * 32 + n * 16 + (lane & 15);
      const int o = col & 1023;
      const float bv = bias[col];
#pragma unroll
      for (int i = 0; i < 8; ++i) {
        const int qa = i >> 2, m = i & 3;
#pragma unroll
        for (int r = 0; r < 4; ++r) {
          const int mg = brow + qa * 128 + wr * 64 + m * 16 + (lane >> 4) * 4 + r;
          dst[(size_t)mg * 1024 + o] = (__bf16)((acc[i][j][r] + bv) * scale);
        }
      }
    }
  } else {
    // V: write transposed Vt[b][d][n]; 4 consecutive n-rows pack into one 8B store
#pragma unroll
    for (int j = 0; j < 4; ++j) {
      const int qb = j >> 1, n = j & 1;
      const int col = bcol + qb * 128 + wc * 32 + n * 16 + (lane & 15);
      const int o = col & 1023;                // d index
      const float bv = bias[col];
#pragma unroll
      for (int i = 0; i < 8; ++i) {
        const int qa = i >> 2, m = i & 3;
        const int mg0 = brow + qa * 128 + wr * 64 + m * 16 + (lane >> 4) * 4;
        const int b = mg0 >> 11, nr = mg0 & 2047;
        bf16x4 v;
#pragma unroll
        for (int r = 0; r < 4; ++r) v[r] = (__bf16)(acc[i][j][r] + bv);
        *(bf16x4*)&Vt[(size_t)b * 2097152 + (size_t)o * 2048 + nr] = v;
      }
    }
  }
}

// ------- kernel 2: Pu = exp(QK^T/32 - 16) bf16 + row-sum atomics -----------
__global__ __launch_bounds__(512, 2) void scores_gemm256(const __bf16* __restrict__ Q,
                                                         const __bf16* __restrict__ Kb,
                                                         __bf16* __restrict__ Pu,
                                                         float* __restrict__ rowsum) {
  __shared__ __bf16 lds[65536];
  ACC_ZERO();
  int bid = (int)blockIdx.x;                  // 512 blocks: XCD swizzle, batch-per-XCD
  const int wg = (bid & 7) * 64 + (bid >> 3);
  const int brow = (wg & 7) * 256, bcol = ((wg >> 3) & 7) * 256, z = wg >> 6;
  gemm256_mainloop(Q + (size_t)z * 2048 * 1024 + (size_t)brow * 1024,
                   Kb + (size_t)z * 2048 * 1024 + (size_t)bcol * 1024,
                   1024, 1024, 1024, lds, acc);
  const int lane = threadIdx.x & 63, wid = threadIdx.x >> 6;
  const int wr = wid >> 2, wc = wid & 3;
  const int fr = lane & 15, g4 = (lane >> 4) * 4;
#pragma unroll
  for (int i = 0; i < 8; ++i) {
    const int qa = i >> 2, m = i & 3;
#pragma unroll
    for (int r = 0; r < 4; ++r) {
      const int mg = brow + qa * 128 + wr * 64 + m * 16 + g4 + r;
      float part = 0.0f;
#pragma unroll
      for (int j = 0; j < 4; ++j) {
        const int qb = j >> 1, n = j & 1;
        const int o = bcol + qb * 128 + wc * 32 + n * 16 + fr;
        const float e = __expf(acc[i][j][r] - 16.0f);   // |S|<~6 -> e in bf16 range
        part += e;
        Pu[((size_t)(z * 2048 + mg)) * 2048 + o] = (__bf16)e;
      }
      // reduce the wave's 64-col partial across the 16 lanes sharing this row
      part += __shfl_xor(part, 1, 64);
      part += __shfl_xor(part, 2, 64);
      part += __shfl_xor(part, 4, 64);
      part += __shfl_xor(part, 8, 64);
      if (fr == 0) atomicAdd(&rowsum[z * 2048 + mg], part);
    }
  }
}

// ------- kernel 3: out = (Pu @ V) * 1/rowsum  (via Vt, B^T form) -----------
__global__ __launch_bounds__(512, 2) void pv_gemm256(const __bf16* __restrict__ P,
                                                     const __bf16* __restrict__ Vt,
                                                     const float* __restrict__ rowsum,
                                                     float* __restrict__ O) {
  __shared__ __bf16 lds[65536];
  ACC_ZERO();
  int bid = (int)blockIdx.x;                  // 256 blocks: XCD swizzle, batch-per-XCD
  const int wg = (bid & 7) * 32 + (bid >> 3);
  const int brow = (wg & 7) * 256, bcol = ((wg >> 3) & 3) * 256, z = wg >> 5;
  gemm256_mainloop(P + (size_t)(z * 2048 + brow) * 2048,
                   Vt + (size_t)z * 1024 * 2048 + (size_t)bcol * 2048,
                   2048, 2048, 2048, lds, acc);
  const int lane = threadIdx.x & 63, wid = threadIdx.x >> 6;
  const int wr = wid >> 2, wc = wid & 3;
  const int fr = lane & 15, g4 = (lane >> 4) * 4;
#pragma unroll
  for (int i = 0; i < 8; ++i) {
    const int qa = i >> 2, m = i & 3;
#pragma unroll
    for (int r = 0; r < 4; ++r) {
      const int mg = brow + qa * 128 + wr * 64 + m * 16 + g4 + r;
      const float inv = 1.0f / rowsum[z * 2048 + mg];
#pragma unroll
      for (int j = 0; j < 4; ++j) {
        const int qb = j >> 1, n = j & 1;
        const int o = bcol + qb * 128 + wc * 32 + n * 16 + fr;
        O[((size_t)(z * 2048 + mg)) * 1024 + o] = acc[i][j][r] * inv;
      }
    }
  }
}

extern "C" void kernel_launch(void* const* d_in, const int* in_sizes, int n_in,
                              void* d_out, int out_size, void* d_ws, size_t ws_size,
                              hipStream_t stream) {
  (void)in_sizes; (void)n_in; (void)out_size; (void)ws_size;
  const float* x    = (const float*)d_in[0];
  const float* W    = (const float*)d_in[1];
  const float* bias = (const float*)d_in[2];
  float* out = (float*)d_out;
  char* ws = (char*)d_ws;
  const size_t MB = 1u << 20;
  __bf16* x_bf = (__bf16*)(ws + 0);
  __bf16* W_bf = (__bf16*)(ws + 32 * MB);
  __bf16* Qb   = (__bf16*)(ws + 38 * MB);
  __bf16* Kb   = (__bf16*)(ws + 70 * MB);
  __bf16* Pu   = (__bf16*)(ws + 102 * MB);   // exp(S-16) bf16
  __bf16* Vt   = (__bf16*)(ws + 166 * MB);   // V^T, written by qkv epilogue
  float* rowsum = (float*)(ws + 198 * MB);   // f32[16384], zeroed by cvt_fused

  cvt_fused<<<2048, 256, 0, stream>>>(x, W, x_bf, W_bf, rowsum);
  qkv_gemm256<<<768, 512, 0, stream>>>(x_bf, W_bf, bias, Qb, Kb, Vt);
  scores_gemm256<<<512, 512, 0, stream>>>(Qb, Kb, Pu, rowsum);
  pv_gemm256<<<256, 512, 0, stream>>>(Pu, Vt, rowsum, out);
}